// Round 9
// baseline (342.807 us; speedup 1.0000x reference)
//
#include <hip/hip_runtime.h>

#define NN 100000
#define NE 1600000
#define INC 512
#define HID 128
#define OUTC 64
#define BN_EPS 1e-5f

#define GS_B 1024
#define NSCB 98                   // scan blocks for NBUK*NBLK (=100096 <= 100352)

#define NBLK 256
#define CHUNK (NE / NBLK)         // 6250 exactly
#define BSH 8
#define NBUK ((NN + 255) >> 8)    // 391 buckets of 256 nodes

#define G1_TOTAL 782              // ceil(NN/128)
#define G1A 352
#define G1B 144
#define G1C 286                   // 352+144+286 = 782

#define APAD 72                   // LDS row stride in shorts (144B -> 2-way alias, free)
#define SMEM_BYTES (128 * APAD * 2 * 2)   // 36864: gemm1 As+Bs (128 rows each)

typedef __attribute__((ext_vector_type(8))) short short8v;
typedef __attribute__((ext_vector_type(4))) float f32x4;

__device__ __forceinline__ unsigned short f2bf(float f) {
    unsigned u = __float_as_uint(f);
    u += 0x7FFFu + ((u >> 16) & 1u);     // round-to-nearest-even
    return (unsigned short)(u >> 16);
}

// packed f32x2 -> bf16x2 (RNE), D[15:0]=bf16(lo), D[31:16]=bf16(hi)
__device__ __forceinline__ unsigned cvtpk(float lo, float hi) {
    unsigned r;
    asm("v_cvt_pk_bf16_f32 %0, %1, %2" : "=v"(r) : "v"(lo), "v"(hi));
    return r;
}

__device__ __forceinline__ float bflo(unsigned u) { return __uint_as_float(u << 16); }
__device__ __forceinline__ float bfhi(unsigned u) { return __uint_as_float(u & 0xFFFF0000u); }

// scan the 98 raw block totals into an exclusive prefix, in LDS (per-block redundant)
__device__ __forceinline__ void scan_bsum(const int* __restrict__ bsum2, int* spref) {
    int tid = threadIdx.x;
    if (tid < NSCB) spref[tid] = bsum2[tid];
    __syncthreads();
    if (tid == 0) {
        int run = 0;
        #pragma unroll 1
        for (int i = 0; i < NSCB; ++i) { int t = spref[i]; spref[i] = run; run += t; }
    }
    __syncthreads();
}

// ---------------- fused: W1->bf16T + bucket histogram + BN-acc zero ----------------

__global__ __launch_bounds__(256) void k_pre(const int* __restrict__ col, int* __restrict__ bhist,
                                             const float* __restrict__ W1, unsigned short* __restrict__ W1T,
                                             float* bnsum, float* bnsumsq) {
    __shared__ int lc[NBUK];
    int tid = threadIdx.x, blk = blockIdx.x;
    int i = blk * 256 + tid;                     // 65536 W1 elements, grid is exactly 256 blocks
    W1T[(size_t)(i & 127) * INC + (i >> 7)] = f2bf(W1[i]);
    if (blk == 0 && tid < HID) { bnsum[tid] = 0.f; bnsumsq[tid] = 0.f; }
    for (int q = tid; q < NBUK; q += 256) lc[q] = 0;
    __syncthreads();
    int s = blk * CHUNK, e = s + CHUNK;
    for (int j = s + tid; j < e; j += 256)
        atomicAdd(&lc[col[j] >> BSH], 1);
    __syncthreads();
    for (int q = tid; q < NBUK; q += 256)
        bhist[q * NBLK + blk] = lc[q];
}

// generic scan: per-block exclusive prefix (in-place safe) + raw block totals
__global__ void k_gscanA(const int* __restrict__ src, int* __restrict__ dst,
                         int* __restrict__ bsum, int n) {
    __shared__ int s[GS_B];
    int tid = threadIdx.x;
    int i = blockIdx.x * GS_B + tid;
    int v = (i < n) ? src[i] : 0;
    s[tid] = v;
    __syncthreads();
    for (int off = 1; off < GS_B; off <<= 1) {
        int t = (tid >= off) ? s[tid - off] : 0;
        __syncthreads();
        s[tid] += t;
        __syncthreads();
    }
    if (i < n) dst[i] = s[tid] - v;
    if (tid == GS_B - 1) bsum[blockIdx.x] = s[tid];
}

// ---------------- device bodies for the fat kernels ----------------

// partition edges into buckets; entry = row | (local_col << 24)
__device__ void dev_bpart(char* smem, const int* __restrict__ row, const int* __restrict__ col,
                          const int* __restrict__ sb, const int* __restrict__ bsum2,
                          unsigned* __restrict__ ebuk, int blk) {
    int* lcur = (int*)smem;                       // NBUK ints
    int* spref = (int*)(smem + ((NBUK * 4 + 15) & ~15));  // NSCB ints
    int tid = threadIdx.x;
    scan_bsum(bsum2, spref);
    for (int i = tid; i < NBUK; i += 256) {
        int idx = i * NBLK + blk;
        lcur[i] = sb[idx] + spref[idx >> 10];
    }
    __syncthreads();
    int s = blk * CHUNK, e = s + CHUNK;
    for (int j = s + tid; j < e; j += 256) {
        int r = row[j], c = col[j];
        int p = atomicAdd(&lcur[c >> BSH], 1);
        ebuk[p] = (unsigned)r | ((unsigned)(c & 255) << 24);
    }
}

// per-bucket: node counts -> deg[], local exclusive scan -> rowptr[]
__device__ void dev_nprep(char* smem, const unsigned* __restrict__ ebuk,
                          const int* __restrict__ sb, const int* __restrict__ bsum2,
                          int* __restrict__ deg, int* __restrict__ rowptr, int b) {
    int* lc = (int*)smem;                         // 256
    int* sc = (int*)(smem + 1024);                // 256
    int* spref = (int*)(smem + 2048);             // NSCB
    int tid = threadIdx.x;
    scan_bsum(bsum2, spref);
    lc[tid] = 0;
    __syncthreads();
    int i0 = b * NBLK;
    int s = sb[i0] + spref[i0 >> 10];
    int e2 = (b + 1 < NBUK) ? (sb[i0 + NBLK] + spref[(i0 + NBLK) >> 10]) : NE;
    for (int j = s + tid; j < e2; j += 256)
        atomicAdd(&lc[ebuk[j] >> 24], 1);
    __syncthreads();
    int v = lc[tid];
    sc[tid] = v;
    __syncthreads();
    for (int off = 1; off < 256; off <<= 1) {
        int t = (tid >= off) ? sc[tid - off] : 0;
        __syncthreads();
        sc[tid] += t;
        __syncthreads();
    }
    int node = (b << BSH) + tid;
    if (node < NN) {
        deg[node] = v;
        rowptr[node] = s + sc[tid] - v;
    }
    if (b == NBUK - 1 && tid == 0) rowptr[NN] = NE;
}

// scatter csr entries: entry = row | (deg[row] << 17)
__device__ void dev_bfill(char* smem, const unsigned* __restrict__ ebuk,
                          const int* __restrict__ sb, const int* __restrict__ bsum2,
                          const int* __restrict__ rowptr, const int* __restrict__ deg,
                          unsigned* __restrict__ csr, int b) {
    int* lcur = (int*)smem;                       // 256
    int* spref = (int*)(smem + 1024);             // NSCB
    int tid = threadIdx.x;
    scan_bsum(bsum2, spref);
    int node0 = b << BSH;
    int node = node0 + tid;
    lcur[tid] = (node < NN) ? rowptr[node] : 0;
    __syncthreads();
    int i0 = b * NBLK;
    int s = sb[i0] + spref[i0 >> 10];
    int e2 = (b + 1 < NBUK) ? (sb[i0 + NBLK] + spref[(i0 + NBLK) >> 10]) : NE;
    for (int j = s + tid; j < e2; j += 256) {
        unsigned rc = ebuk[j];
        int li = rc >> 24;
        int r = rc & 0xFFFFFF;
        int p = atomicAdd(&lcur[li], 1);
        csr[p] = (unsigned)r | ((unsigned)deg[r] << 17);
    }
}

// GEMM1 (MFMA) block body: 128 rows x 128 cols per block, 4 waves, BK=64.
// register-prefetch double-stage; operands swapped so lane owns 4 consecutive channels.
#define G1BK 64

__device__ void dev_gemm1(char* smem, const float* __restrict__ x,
                          const unsigned short* __restrict__ W1T,
                          unsigned short* __restrict__ h1b, int mblk) {
    unsigned short (*As)[APAD] = (unsigned short (*)[APAD])smem;
    unsigned short (*Bs)[APAD] = (unsigned short (*)[APAD])(smem + 128 * APAD * 2);
    int tid = threadIdx.x;
    int m0 = mblk * 128;
    int w = tid >> 6;
    int lane = tid & 63;

    f32x4 acc[8][2];
    #pragma unroll
    for (int mr = 0; mr < 8; ++mr)
        #pragma unroll
        for (int cb = 0; cb < 2; ++cb) acc[mr][cb] = (f32x4){0.f, 0.f, 0.f, 0.f};

    int ar = tid >> 1;                 // 0..127
    int ak = (tid & 1) * 32;           // 0 or 32
    int arow = m0 + ar; if (arow >= NN) arow = NN - 1;
    const float* xr = x + (size_t)arow * INC;
    int br = tid >> 1;
    int bk = (tid & 1) * 32;
    const unsigned short* wr = W1T + (size_t)br * INC;

    int frow = lane & 15;
    int fk = (lane >> 4) * 8;

    float4 pv[8];
    short8v pb[4];
    #pragma unroll
    for (int q = 0; q < 8; ++q) pv[q] = *(const float4*)(xr + ak + q * 4);
    #pragma unroll
    for (int q = 0; q < 4; ++q) pb[q] = *(const short8v*)(wr + bk + q * 8);

    for (int k0 = 0; k0 < INC; k0 += G1BK) {
        #pragma unroll
        for (int q = 0; q < 8; ++q)
            *(uint2*)&As[ar][ak + q * 4] = make_uint2(cvtpk(pv[q].x, pv[q].y), cvtpk(pv[q].z, pv[q].w));
        #pragma unroll
        for (int q = 0; q < 4; ++q)
            *(short8v*)&Bs[br][bk + q * 8] = pb[q];
        __syncthreads();
        if (k0 + G1BK < INC) {
            #pragma unroll
            for (int q = 0; q < 8; ++q) pv[q] = *(const float4*)(xr + k0 + G1BK + ak + q * 4);
            #pragma unroll
            for (int q = 0; q < 4; ++q) pb[q] = *(const short8v*)(wr + k0 + G1BK + bk + q * 8);
        }
        #pragma unroll
        for (int kk = 0; kk < G1BK; kk += 32) {
            short8v a[8], b[2];
            #pragma unroll
            for (int mr = 0; mr < 8; ++mr)
                a[mr] = *(const short8v*)&As[16 * mr + frow][kk + fk];   // x nodes (B operand)
            #pragma unroll
            for (int cb = 0; cb < 2; ++cb)
                b[cb] = *(const short8v*)&Bs[32 * w + 16 * cb + frow][kk + fk];  // W channels (A operand)
            #pragma unroll
            for (int mr = 0; mr < 8; ++mr)
                #pragma unroll
                for (int cb = 0; cb < 2; ++cb)
                    acc[mr][cb] = __builtin_amdgcn_mfma_f32_16x16x32_bf16(b[cb], a[mr], acc[mr][cb], 0, 0, 0);
        }
        __syncthreads();
    }
    int ncol = lane & 15;
    int r4 = (lane >> 4) * 4;
    #pragma unroll
    for (int mr = 0; mr < 8; ++mr) {
        int node = m0 + 16 * mr + ncol;
        if (node < NN) {
            #pragma unroll
            for (int cb = 0; cb < 2; ++cb) {
                int ch = 32 * w + 16 * cb + r4;
                *(uint2*)&h1b[(size_t)node * HID + ch] =
                    make_uint2(cvtpk(acc[mr][cb][0], acc[mr][cb][1]),
                               cvtpk(acc[mr][cb][2], acc[mr][cb][3]));
            }
        }
    }
}

// ---------------- fat kernels: CSR stage + gemm1 slice ----------------

__global__ __launch_bounds__(256) void k_fuse1(const int* __restrict__ row, const int* __restrict__ col,
                                               const int* __restrict__ sb, const int* __restrict__ bsum2,
                                               unsigned* __restrict__ ebuk,
                                               const float* __restrict__ x,
                                               const unsigned short* __restrict__ W1T,
                                               unsigned short* __restrict__ h1b) {
    __shared__ __align__(16) char smem[SMEM_BYTES];
    if (blockIdx.x < NBLK) dev_bpart(smem, row, col, sb, bsum2, ebuk, blockIdx.x);
    else                   dev_gemm1(smem, x, W1T, h1b, blockIdx.x - NBLK);
}

__global__ __launch_bounds__(256) void k_fuse2(const unsigned* __restrict__ ebuk,
                                               const int* __restrict__ sb, const int* __restrict__ bsum2,
                                               int* __restrict__ deg, int* __restrict__ rowptr,
                                               const float* __restrict__ x,
                                               const unsigned short* __restrict__ W1T,
                                               unsigned short* __restrict__ h1b) {
    __shared__ __align__(16) char smem[SMEM_BYTES];
    if (blockIdx.x < NBUK) dev_nprep(smem, ebuk, sb, bsum2, deg, rowptr, blockIdx.x);
    else                   dev_gemm1(smem, x, W1T, h1b, blockIdx.x - NBUK + G1A);
}

__global__ __launch_bounds__(256) void k_fuse3(const unsigned* __restrict__ ebuk,
                                               const int* __restrict__ sb, const int* __restrict__ bsum2,
                                               const int* __restrict__ rowptr, const int* __restrict__ deg,
                                               unsigned* __restrict__ csr,
                                               const float* __restrict__ x,
                                               const unsigned short* __restrict__ W1T,
                                               unsigned short* __restrict__ h1b) {
    __shared__ __align__(16) char smem[SMEM_BYTES];
    if (blockIdx.x < NBUK) dev_bfill(smem, ebuk, sb, bsum2, rowptr, deg, csr, blockIdx.x);
    else                   dev_gemm1(smem, x, W1T, h1b, blockIdx.x - NBUK + G1A + G1B);
}

// ---------------- aggregation 1 (128 ch bf16 -> bf16): 1 wave/node, 16-deep unroll ----------------

__global__ __launch_bounds__(256) void k_agg1(const unsigned short* __restrict__ h1b,
                                              const int* __restrict__ rowptr, const unsigned* __restrict__ csr,
                                              const float* __restrict__ b1, unsigned* __restrict__ aggb) {
    int node = blockIdx.x * 4 + (threadIdx.x >> 6);
    int lane = threadIdx.x & 63;
    const unsigned* hp = (const unsigned*)h1b;     // 64 uints per row (2 bf16 ch each)
    size_t base = (size_t)node * 64 + lane;
    int s = rowptr[node], e = rowptr[node + 1];
    float dnf = (float)(e - s + 1);
    float di = rsqrtf(dnf);
    float wself = di * di;
    unsigned hv = hp[base];
    float sx = wself * bflo(hv);
    float sy = wself * bfhi(hv);
    int j = s;
    for (; j + 16 <= e; j += 16) {
        unsigned c[16], v[16];
        #pragma unroll
        for (int q = 0; q < 16; ++q) c[q] = csr[j + q];
        #pragma unroll
        for (int q = 0; q < 16; ++q) v[q] = hp[(size_t)(c[q] & 0x1FFFF) * 64 + lane];
        #pragma unroll
        for (int q = 0; q < 16; ++q) {
            float ww = rsqrtf(dnf * (float)((c[q] >> 17) + 1));
            sx = fmaf(ww, bflo(v[q]), sx); sy = fmaf(ww, bfhi(v[q]), sy);
        }
    }
    for (; j + 4 <= e; j += 4) {
        unsigned c[4], v[4];
        #pragma unroll
        for (int q = 0; q < 4; ++q) c[q] = csr[j + q];
        #pragma unroll
        for (int q = 0; q < 4; ++q) v[q] = hp[(size_t)(c[q] & 0x1FFFF) * 64 + lane];
        #pragma unroll
        for (int q = 0; q < 4; ++q) {
            float ww = rsqrtf(dnf * (float)((c[q] >> 17) + 1));
            sx = fmaf(ww, bflo(v[q]), sx); sy = fmaf(ww, bfhi(v[q]), sy);
        }
    }
    for (; j < e; ++j) {
        unsigned c = csr[j];
        unsigned v = hp[(size_t)(c & 0x1FFFF) * 64 + lane];
        float ww = rsqrtf(dnf * (float)((c >> 17) + 1));
        sx = fmaf(ww, bflo(v), sx); sy = fmaf(ww, bfhi(v), sy);
    }
    float2 bb = ((const float2*)b1)[lane];
    aggb[base] = cvtpk(sx + bb.x, sy + bb.y);
}

// ---------------- BN stats (from bf16 agg) ----------------

__global__ __launch_bounds__(256) void k_bnstats(const unsigned* __restrict__ aggb,
                                                 float* __restrict__ bnsum, float* __restrict__ bnsumsq) {
    __shared__ float4 ss[256], sq[256];
    int g = threadIdx.x & 31;          // 4-channel group: channels 4g..4g+3
    int h = threadIdx.x >> 5;          // 0..7 row offset
    float4 fs = make_float4(0.f, 0.f, 0.f, 0.f);
    float4 fq = make_float4(0.f, 0.f, 0.f, 0.f);
    int rows_per_block = (NN + gridDim.x - 1) / gridDim.x;
    int r0 = blockIdx.x * rows_per_block;
    int r1 = r0 + rows_per_block; if (r1 > NN) r1 = NN;
    for (int r = r0 + h; r < r1; r += 8) {
        uint2 u = *(const uint2*)(aggb + (size_t)r * 64 + 2 * g);
        float a0 = bflo(u.x), a1 = bfhi(u.x), a2 = bflo(u.y), a3 = bfhi(u.y);
        fs.x += a0; fs.y += a1; fs.z += a2; fs.w += a3;
        fq.x += a0 * a0; fq.y += a1 * a1; fq.z += a2 * a2; fq.w += a3 * a3;
    }
    ss[threadIdx.x] = fs; sq[threadIdx.x] = fq;
    __syncthreads();
    if (threadIdx.x < 32) {
        float4 as = ss[threadIdx.x], aq = sq[threadIdx.x];
        #pragma unroll
        for (int k = 1; k < 8; ++k) {
            float4 bs = ss[k * 32 + threadIdx.x], bq = sq[k * 32 + threadIdx.x];
            as.x += bs.x; as.y += bs.y; as.z += bs.z; as.w += bs.w;
            aq.x += bq.x; aq.y += bq.y; aq.z += bq.z; aq.w += bq.w;
        }
        atomicAdd(&bnsum[4 * g + 0], as.x); atomicAdd(&bnsum[4 * g + 1], as.y);
        atomicAdd(&bnsum[4 * g + 2], as.z); atomicAdd(&bnsum[4 * g + 3], as.w);
        atomicAdd(&bnsumsq[4 * g + 0], aq.x); atomicAdd(&bnsumsq[4 * g + 1], aq.y);
        atomicAdd(&bnsumsq[4 * g + 2], aq.z); atomicAdd(&bnsumsq[4 * g + 3], aq.w);
    }
}

// ---------------- GEMM2 (+inline BN finalize): h2b = relu(bn(aggb)) @ W2 ----------------

__global__ __launch_bounds__(256) void k_gemm2(const unsigned* __restrict__ aggb, const float* __restrict__ W2,
                                               const float* __restrict__ bnsum, const float* __restrict__ bnsumsq,
                                               const float* __restrict__ gamma, const float* __restrict__ beta,
                                               unsigned short* __restrict__ h2b) {
    __shared__ float As2[32][66];
    __shared__ float Bs2[32][OUTC];
    __shared__ float bnsc[HID], bnsh[HID];
    int tid = threadIdx.x;
    if (tid < HID) {
        float mu = bnsum[tid] / (float)NN;
        float var = bnsumsq[tid] / (float)NN - mu * mu;
        float sc = gamma[tid] * rsqrtf(var + BN_EPS);
        bnsc[tid] = sc;
        bnsh[tid] = beta[tid] - mu * sc;
    }
    __syncthreads();
    int m0 = blockIdx.x * 64;
    int tx = tid & 15, ty = tid >> 4;
    float acc[4][4];
    #pragma unroll
    for (int r = 0; r < 4; ++r)
        #pragma unroll
        for (int c = 0; c < 4; ++c) acc[r][c] = 0.f;

    int am = tid >> 3;          // 0..31
    int ak = (tid & 7) * 4;     // 0..28
    int bk = tid >> 4;          // 0..15
    int bc = (tid & 15) * 4;    // 0..60

    for (int k0 = 0; k0 < HID; k0 += 32) {
        #pragma unroll
        for (int h = 0; h < 2; ++h) {
            int m = am + h * 32;
            int rowi = m0 + m; if (rowi >= NN) rowi = NN - 1;
            uint2 u = *(const uint2*)(aggb + (size_t)rowi * 64 + ((k0 + ak) >> 1));
            float4 sc = *(const float4*)&bnsc[k0 + ak];
            float4 sh = *(const float4*)&bnsh[k0 + ak];
            As2[ak + 0][m] = fmaxf(fmaf(bflo(u.x), sc.x, sh.x), 0.f);
            As2[ak + 1][m] = fmaxf(fmaf(bfhi(u.x), sc.y, sh.y), 0.f);
            As2[ak + 2][m] = fmaxf(fmaf(bflo(u.y), sc.z, sh.z), 0.f);
            As2[ak + 3][m] = fmaxf(fmaf(bfhi(u.y), sc.w, sh.w), 0.f);
        }
        #pragma unroll
        for (int h = 0; h < 2; ++h) {
            int k = bk + h * 16;
            *(float4*)&Bs2[k][bc] = *(const float4*)(W2 + (size_t)(k0 + k) * OUTC + bc);
        }
        __syncthreads();
        #pragma unroll
        for (int k = 0; k < 32; ++k) {
            float a[4];
            #pragma unroll
            for (int r = 0; r < 4; ++r) a[r] = As2[k][ty * 4 + r];
            float4 b = *(const float4*)&Bs2[k][tx * 4];
            #pragma unroll
            for (int r = 0; r < 4; ++r) {
                acc[r][0] = fmaf(a[r], b.x, acc[r][0]);
                acc[r][1] = fmaf(a[r], b.y, acc[r][1]);
                acc[r][2] = fmaf(a[r], b.z, acc[r][2]);
                acc[r][3] = fmaf(a[r], b.w, acc[r][3]);
            }
        }
        __syncthreads();
    }
    #pragma unroll
    for (int r = 0; r < 4; ++r) {
        int m = m0 + ty * 4 + r;
        if (m < NN) {
            *(uint2*)(h2b + (size_t)m * OUTC + tx * 4) =
                make_uint2(cvtpk(acc[r][0], acc[r][1]), cvtpk(acc[r][2], acc[r][3]));
        }
    }
}

// ---------------- aggregation 2 (64 ch bf16): 1 wave/node, lane-halves alternate edges ----------------

__global__ __launch_bounds__(256) void k_agg2(const unsigned short* __restrict__ h2b,
                                              const int* __restrict__ rowptr, const unsigned* __restrict__ csr,
                                              const float* __restrict__ b2, float* __restrict__ out) {
    int node = blockIdx.x * 4 + (threadIdx.x >> 6);
    int lane = threadIdx.x & 63;
    int l32 = lane & 31;
    const unsigned* hp = (const unsigned*)h2b;     // 32 uints per row (2 bf16 ch each)
    int s = rowptr[node], e = rowptr[node + 1];
    float dnf = (float)(e - s + 1);
    float di = rsqrtf(dnf);
    float wself = di * di;
    float sx = 0.f, sy = 0.f;
    if (lane < 32) {
        unsigned u = hp[(size_t)node * 32 + l32];
        sx = wself * bflo(u);
        sy = wself * bfhi(u);
    }
    int j = s + (lane >> 5);
    for (; j + 14 < e; j += 16) {
        unsigned c[8], v[8];
        #pragma unroll
        for (int q = 0; q < 8; ++q) c[q] = csr[j + 2 * q];
        #pragma unroll
        for (int q = 0; q < 8; ++q) v[q] = hp[(size_t)(c[q] & 0x1FFFF) * 32 + l32];
        #pragma unroll
        for (int q = 0; q < 8; ++q) {
            float ww = rsqrtf(dnf * (float)((c[q] >> 17) + 1));
            sx = fmaf(ww, bflo(v[q]), sx); sy = fmaf(ww, bfhi(v[q]), sy);
        }
    }
    for (; j + 2 < e; j += 4) {
        unsigned c0 = csr[j], c1 = csr[j + 2];
        unsigned v0 = hp[(size_t)(c0 & 0x1FFFF) * 32 + l32];
        unsigned v1 = hp[(size_t)(c1 & 0x1FFFF) * 32 + l32];
        float w0 = rsqrtf(dnf * (float)((c0 >> 17) + 1));
        float w1 = rsqrtf(dnf * (float)((c1 >> 17) + 1));
        sx = fmaf(w0, bflo(v0), sx); sy = fmaf(w0, bfhi(v0), sy);
        sx = fmaf(w1, bflo(v1), sx); sy = fmaf(w1, bfhi(v1), sy);
    }
    if (j < e) {
        unsigned c = csr[j];
        unsigned v = hp[(size_t)(c & 0x1FFFF) * 32 + l32];
        float ww = rsqrtf(dnf * (float)((c >> 17) + 1));
        sx = fmaf(ww, bflo(v), sx); sy = fmaf(ww, bfhi(v), sy);
    }
    sx += __shfl_xor(sx, 32);
    sy += __shfl_xor(sy, 32);
    if (lane < 32) {
        float2 bb = ((const float2*)b2)[l32];
        ((float2*)out)[(size_t)node * 32 + l32] = make_float2(sx + bb.x, sy + bb.y);
    }
}

// ---------------- launch ----------------

extern "C" void kernel_launch(void* const* d_in, const int* in_sizes, int n_in,
                              void* d_out, int out_size, void* d_ws, size_t ws_size,
                              hipStream_t stream) {
    const float* x     = (const float*)d_in[0];
    const int*   ei    = (const int*)d_in[1];
    const float* W1    = (const float*)d_in[2];
    const float* b1    = (const float*)d_in[3];
    const float* gamma = (const float*)d_in[4];
    const float* beta  = (const float*)d_in[5];
    const float* W2    = (const float*)d_in[6];
    const float* b2    = (const float*)d_in[7];
    const int* row = ei;          // edge_index[0]
    const int* col = ei + NE;     // edge_index[1]
    float* out = (float*)d_out;

    char* wp = (char*)d_ws;
    auto alloc = [&](size_t bytes) -> void* {
        void* p = (void*)wp;
        wp += (bytes + 255) & ~(size_t)255;
        return p;
    };
    unsigned short* h1b = (unsigned short*)alloc((size_t)NN * HID * 2);
    unsigned* aggb = (unsigned*)alloc((size_t)NN * HID * 2);
    unsigned short* h2b = (unsigned short*)alloc((size_t)NN * OUTC * 2);
    int*   deg     = (int*)alloc((size_t)NN * 4);
    float* bnsum   = (float*)alloc(HID * 4);
    float* bnsumsq = (float*)alloc(HID * 4);
    int*   rowptr  = (int*)alloc((size_t)(NN + 1) * 4);
    int*   bhist   = (int*)alloc((size_t)NBUK * NBLK * 4);
    int*   bsum2   = (int*)alloc(NSCB * 4);
    unsigned* ebuk = (unsigned*)alloc((size_t)NE * 4);
    unsigned* csr  = (unsigned*)alloc((size_t)NE * 4);
    unsigned short* W1T = (unsigned short*)alloc((size_t)HID * INC * 2);

    hipLaunchKernelGGL(k_pre,    dim3(NBLK), dim3(256), 0, stream, col, bhist, W1, W1T, bnsum, bnsumsq);
    hipLaunchKernelGGL(k_gscanA, dim3(NSCB), dim3(GS_B), 0, stream, bhist, bhist, bsum2, NBUK * NBLK);
    hipLaunchKernelGGL(k_fuse1,  dim3(NBLK + G1A), dim3(256), 0, stream, row, col, bhist, bsum2, ebuk, x, W1T, h1b);
    hipLaunchKernelGGL(k_fuse2,  dim3(NBUK + G1B), dim3(256), 0, stream, ebuk, bhist, bsum2, deg, rowptr, x, W1T, h1b);
    hipLaunchKernelGGL(k_fuse3,  dim3(NBUK + G1C), dim3(256), 0, stream, ebuk, bhist, bsum2, rowptr, deg, csr, x, W1T, h1b);
    hipLaunchKernelGGL(k_agg1,   dim3(NN / 4), dim3(256), 0, stream, h1b, rowptr, csr, b1, aggb);
    hipLaunchKernelGGL(k_bnstats, dim3(256), dim3(256), 0, stream, aggb, bnsum, bnsumsq);
    hipLaunchKernelGGL(k_gemm2,  dim3((NN + 63) / 64), dim3(256), 0, stream, aggb, W2, bnsum, bnsumsq, gamma, beta, h2b);
    hipLaunchKernelGGL(k_agg2,   dim3(NN / 4), dim3(256), 0, stream, h2b, rowptr, csr, b2, out);
}

// Round 10
// 324.924 us; speedup vs baseline: 1.0550x; 1.0550x over previous
//
#include <hip/hip_runtime.h>

#define NN 100000
#define NE 1600000
#define INC 512
#define HID 128
#define OUTC 64
#define BN_EPS 1e-5f

#define GS_B 1024
#define NSCB 98                   // scan blocks for NBUK*NBLK (=100096 <= 100352)

#define NBLK 256
#define CHUNK (NE / NBLK)         // 6250 exactly
#define BSH 8
#define NBUK ((NN + 255) >> 8)    // 391 buckets of 256 nodes

#define G1_TOTAL 1563             // ceil(NN/64)
#define G1A 704
#define G1B 288
#define G1C 571                   // 704+288+571 = 1563

#define APAD 72                   // LDS row stride in shorts (144B -> 2-way alias, free)
#define SMEM_BYTES (64 * APAD * 2 + 128 * APAD * 2)   // 27648: gemm1 As+Bs

typedef __attribute__((ext_vector_type(8))) short short8v;
typedef __attribute__((ext_vector_type(4))) float f32x4;

__device__ __forceinline__ unsigned short f2bf(float f) {
    unsigned u = __float_as_uint(f);
    u += 0x7FFFu + ((u >> 16) & 1u);     // round-to-nearest-even
    return (unsigned short)(u >> 16);
}

// packed f32x2 -> bf16x2 (RNE), D[15:0]=bf16(lo), D[31:16]=bf16(hi)
__device__ __forceinline__ unsigned cvtpk(float lo, float hi) {
    unsigned r;
    asm("v_cvt_pk_bf16_f32 %0, %1, %2" : "=v"(r) : "v"(lo), "v"(hi));
    return r;
}

__device__ __forceinline__ float bflo(unsigned u) { return __uint_as_float(u << 16); }
__device__ __forceinline__ float bfhi(unsigned u) { return __uint_as_float(u & 0xFFFF0000u); }

// scan the 98 raw block totals into an exclusive prefix, in LDS (per-block redundant)
__device__ __forceinline__ void scan_bsum(const int* __restrict__ bsum2, int* spref) {
    int tid = threadIdx.x;
    if (tid < NSCB) spref[tid] = bsum2[tid];
    __syncthreads();
    if (tid == 0) {
        int run = 0;
        #pragma unroll 1
        for (int i = 0; i < NSCB; ++i) { int t = spref[i]; spref[i] = run; run += t; }
    }
    __syncthreads();
}

// ---------------- fused: W1->bf16T + bucket histogram + BN-acc zero ----------------

__global__ __launch_bounds__(256) void k_pre(const int* __restrict__ col, int* __restrict__ bhist,
                                             const float* __restrict__ W1, unsigned short* __restrict__ W1T,
                                             float* bnsum, float* bnsumsq) {
    __shared__ int lc[NBUK];
    int tid = threadIdx.x, blk = blockIdx.x;
    int i = blk * 256 + tid;                     // 65536 W1 elements, grid is exactly 256 blocks
    W1T[(size_t)(i & 127) * INC + (i >> 7)] = f2bf(W1[i]);
    if (blk == 0 && tid < HID) { bnsum[tid] = 0.f; bnsumsq[tid] = 0.f; }
    for (int q = tid; q < NBUK; q += 256) lc[q] = 0;
    __syncthreads();
    int s = blk * CHUNK, e = s + CHUNK;
    for (int j = s + tid; j < e; j += 256)
        atomicAdd(&lc[col[j] >> BSH], 1);
    __syncthreads();
    for (int q = tid; q < NBUK; q += 256)
        bhist[q * NBLK + blk] = lc[q];
}

// generic scan: per-block exclusive prefix (in-place safe) + raw block totals
__global__ void k_gscanA(const int* __restrict__ src, int* __restrict__ dst,
                         int* __restrict__ bsum, int n) {
    __shared__ int s[GS_B];
    int tid = threadIdx.x;
    int i = blockIdx.x * GS_B + tid;
    int v = (i < n) ? src[i] : 0;
    s[tid] = v;
    __syncthreads();
    for (int off = 1; off < GS_B; off <<= 1) {
        int t = (tid >= off) ? s[tid - off] : 0;
        __syncthreads();
        s[tid] += t;
        __syncthreads();
    }
    if (i < n) dst[i] = s[tid] - v;
    if (tid == GS_B - 1) bsum[blockIdx.x] = s[tid];
}

// ---------------- device bodies for the fat kernels ----------------

// partition edges into buckets; entry = row | (local_col << 24)
__device__ void dev_bpart(char* smem, const int* __restrict__ row, const int* __restrict__ col,
                          const int* __restrict__ sb, const int* __restrict__ bsum2,
                          unsigned* __restrict__ ebuk, int blk) {
    int* lcur = (int*)smem;                       // NBUK ints
    int* spref = (int*)(smem + ((NBUK * 4 + 15) & ~15));  // NSCB ints
    int tid = threadIdx.x;
    scan_bsum(bsum2, spref);
    for (int i = tid; i < NBUK; i += 256) {
        int idx = i * NBLK + blk;
        lcur[i] = sb[idx] + spref[idx >> 10];
    }
    __syncthreads();
    int s = blk * CHUNK, e = s + CHUNK;
    for (int j = s + tid; j < e; j += 256) {
        int r = row[j], c = col[j];
        int p = atomicAdd(&lcur[c >> BSH], 1);
        ebuk[p] = (unsigned)r | ((unsigned)(c & 255) << 24);
    }
}

// per-bucket: node counts -> deg[], local exclusive scan -> rowptr[]
__device__ void dev_nprep(char* smem, const unsigned* __restrict__ ebuk,
                          const int* __restrict__ sb, const int* __restrict__ bsum2,
                          int* __restrict__ deg, int* __restrict__ rowptr, int b) {
    int* lc = (int*)smem;                         // 256
    int* sc = (int*)(smem + 1024);                // 256
    int* spref = (int*)(smem + 2048);             // NSCB
    int tid = threadIdx.x;
    scan_bsum(bsum2, spref);
    lc[tid] = 0;
    __syncthreads();
    int i0 = b * NBLK;
    int s = sb[i0] + spref[i0 >> 10];
    int e2 = (b + 1 < NBUK) ? (sb[i0 + NBLK] + spref[(i0 + NBLK) >> 10]) : NE;
    for (int j = s + tid; j < e2; j += 256)
        atomicAdd(&lc[ebuk[j] >> 24], 1);
    __syncthreads();
    int v = lc[tid];
    sc[tid] = v;
    __syncthreads();
    for (int off = 1; off < 256; off <<= 1) {
        int t = (tid >= off) ? sc[tid - off] : 0;
        __syncthreads();
        sc[tid] += t;
        __syncthreads();
    }
    int node = (b << BSH) + tid;
    if (node < NN) {
        deg[node] = v;
        rowptr[node] = s + sc[tid] - v;
    }
    if (b == NBUK - 1 && tid == 0) rowptr[NN] = NE;
}

// scatter csr entries: entry = row | (deg[row] << 17)
__device__ void dev_bfill(char* smem, const unsigned* __restrict__ ebuk,
                          const int* __restrict__ sb, const int* __restrict__ bsum2,
                          const int* __restrict__ rowptr, const int* __restrict__ deg,
                          unsigned* __restrict__ csr, int b) {
    int* lcur = (int*)smem;                       // 256
    int* spref = (int*)(smem + 1024);             // NSCB
    int tid = threadIdx.x;
    scan_bsum(bsum2, spref);
    int node0 = b << BSH;
    int node = node0 + tid;
    lcur[tid] = (node < NN) ? rowptr[node] : 0;
    __syncthreads();
    int i0 = b * NBLK;
    int s = sb[i0] + spref[i0 >> 10];
    int e2 = (b + 1 < NBUK) ? (sb[i0 + NBLK] + spref[(i0 + NBLK) >> 10]) : NE;
    for (int j = s + tid; j < e2; j += 256) {
        unsigned rc = ebuk[j];
        int li = rc >> 24;
        int r = rc & 0xFFFFFF;
        int p = atomicAdd(&lcur[li], 1);
        csr[p] = (unsigned)r | ((unsigned)deg[r] << 17);
    }
}

// GEMM1 (MFMA) block body: 64 rows x 128 cols per block, 4 waves, BK=64.
// register-prefetch double-stage; operands swapped so lane owns 4 consecutive channels.
#define G1BK 64

__device__ void dev_gemm1(char* smem, const float* __restrict__ x,
                          const unsigned short* __restrict__ W1T,
                          unsigned short* __restrict__ h1b, int mblk) {
    unsigned short (*As)[APAD] = (unsigned short (*)[APAD])smem;
    unsigned short (*Bs)[APAD] = (unsigned short (*)[APAD])(smem + 64 * APAD * 2);
    int tid = threadIdx.x;
    int m0 = mblk * 64;
    int w = tid >> 6;
    int lane = tid & 63;

    f32x4 acc[4][2];
    #pragma unroll
    for (int mr = 0; mr < 4; ++mr)
        #pragma unroll
        for (int cb = 0; cb < 2; ++cb) acc[mr][cb] = (f32x4){0.f, 0.f, 0.f, 0.f};

    int ar = tid >> 2;
    int ak = (tid & 3) * 16;
    int arow = m0 + ar; if (arow >= NN) arow = NN - 1;
    const float* xr = x + (size_t)arow * INC;
    int br = tid >> 1;
    int bk = (tid & 1) * 32;
    const unsigned short* wr = W1T + (size_t)br * INC;

    int frow = lane & 15;
    int fk = (lane >> 4) * 8;

    float4 pv[4];
    short8v pb[4];
    #pragma unroll
    for (int q = 0; q < 4; ++q) pv[q] = *(const float4*)(xr + ak + q * 4);
    #pragma unroll
    for (int q = 0; q < 4; ++q) pb[q] = *(const short8v*)(wr + bk + q * 8);

    for (int k0 = 0; k0 < INC; k0 += G1BK) {
        #pragma unroll
        for (int q = 0; q < 4; ++q)
            *(uint2*)&As[ar][ak + q * 4] = make_uint2(cvtpk(pv[q].x, pv[q].y), cvtpk(pv[q].z, pv[q].w));
        #pragma unroll
        for (int q = 0; q < 4; ++q)
            *(short8v*)&Bs[br][bk + q * 8] = pb[q];
        __syncthreads();
        if (k0 + G1BK < INC) {
            #pragma unroll
            for (int q = 0; q < 4; ++q) pv[q] = *(const float4*)(xr + k0 + G1BK + ak + q * 4);
            #pragma unroll
            for (int q = 0; q < 4; ++q) pb[q] = *(const short8v*)(wr + k0 + G1BK + bk + q * 8);
        }
        #pragma unroll
        for (int kk = 0; kk < G1BK; kk += 32) {
            short8v a[4], b[2];
            #pragma unroll
            for (int mr = 0; mr < 4; ++mr)
                a[mr] = *(const short8v*)&As[16 * mr + frow][kk + fk];   // x nodes (B operand)
            #pragma unroll
            for (int cb = 0; cb < 2; ++cb)
                b[cb] = *(const short8v*)&Bs[32 * w + 16 * cb + frow][kk + fk];  // W channels (A operand)
            #pragma unroll
            for (int mr = 0; mr < 4; ++mr)
                #pragma unroll
                for (int cb = 0; cb < 2; ++cb)
                    acc[mr][cb] = __builtin_amdgcn_mfma_f32_16x16x32_bf16(b[cb], a[mr], acc[mr][cb], 0, 0, 0);
        }
        __syncthreads();
    }
    int ncol = lane & 15;
    int r4 = (lane >> 4) * 4;
    #pragma unroll
    for (int mr = 0; mr < 4; ++mr) {
        int node = m0 + 16 * mr + ncol;
        if (node < NN) {
            #pragma unroll
            for (int cb = 0; cb < 2; ++cb) {
                int ch = 32 * w + 16 * cb + r4;
                *(uint2*)&h1b[(size_t)node * HID + ch] =
                    make_uint2(cvtpk(acc[mr][cb][0], acc[mr][cb][1]),
                               cvtpk(acc[mr][cb][2], acc[mr][cb][3]));
            }
        }
    }
}

// ---------------- fat kernels: CSR stage + gemm1 slice ----------------

__global__ __launch_bounds__(256) void k_fuse1(const int* __restrict__ row, const int* __restrict__ col,
                                               const int* __restrict__ sb, const int* __restrict__ bsum2,
                                               unsigned* __restrict__ ebuk,
                                               const float* __restrict__ x,
                                               const unsigned short* __restrict__ W1T,
                                               unsigned short* __restrict__ h1b) {
    __shared__ __align__(16) char smem[SMEM_BYTES];
    if (blockIdx.x < NBLK) dev_bpart(smem, row, col, sb, bsum2, ebuk, blockIdx.x);
    else                   dev_gemm1(smem, x, W1T, h1b, blockIdx.x - NBLK);
}

__global__ __launch_bounds__(256) void k_fuse2(const unsigned* __restrict__ ebuk,
                                               const int* __restrict__ sb, const int* __restrict__ bsum2,
                                               int* __restrict__ deg, int* __restrict__ rowptr,
                                               const float* __restrict__ x,
                                               const unsigned short* __restrict__ W1T,
                                               unsigned short* __restrict__ h1b) {
    __shared__ __align__(16) char smem[SMEM_BYTES];
    if (blockIdx.x < NBUK) dev_nprep(smem, ebuk, sb, bsum2, deg, rowptr, blockIdx.x);
    else                   dev_gemm1(smem, x, W1T, h1b, blockIdx.x - NBUK + G1A);
}

__global__ __launch_bounds__(256) void k_fuse3(const unsigned* __restrict__ ebuk,
                                               const int* __restrict__ sb, const int* __restrict__ bsum2,
                                               const int* __restrict__ rowptr, const int* __restrict__ deg,
                                               unsigned* __restrict__ csr,
                                               const float* __restrict__ x,
                                               const unsigned short* __restrict__ W1T,
                                               unsigned short* __restrict__ h1b) {
    __shared__ __align__(16) char smem[SMEM_BYTES];
    if (blockIdx.x < NBUK) dev_bfill(smem, ebuk, sb, bsum2, rowptr, deg, csr, blockIdx.x);
    else                   dev_gemm1(smem, x, W1T, h1b, blockIdx.x - NBUK + G1A + G1B);
}

// ---------------- aggregation 1 (128 ch bf16 -> bf16): 1 wave/node, 16-deep unroll ----------------

__global__ __launch_bounds__(256) void k_agg1(const unsigned short* __restrict__ h1b,
                                              const int* __restrict__ rowptr, const unsigned* __restrict__ csr,
                                              const float* __restrict__ b1, unsigned* __restrict__ aggb) {
    int node = blockIdx.x * 4 + (threadIdx.x >> 6);
    int lane = threadIdx.x & 63;
    const unsigned* hp = (const unsigned*)h1b;     // 64 uints per row (2 bf16 ch each)
    size_t base = (size_t)node * 64 + lane;
    int s = rowptr[node], e = rowptr[node + 1];
    float dnf = (float)(e - s + 1);
    float di = rsqrtf(dnf);
    float wself = di * di;
    unsigned hv = hp[base];
    float sx = wself * bflo(hv);
    float sy = wself * bfhi(hv);
    int j = s;
    for (; j + 16 <= e; j += 16) {
        unsigned c[16], v[16];
        #pragma unroll
        for (int q = 0; q < 16; ++q) c[q] = csr[j + q];
        #pragma unroll
        for (int q = 0; q < 16; ++q) v[q] = hp[(size_t)(c[q] & 0x1FFFF) * 64 + lane];
        #pragma unroll
        for (int q = 0; q < 16; ++q) {
            float ww = rsqrtf(dnf * (float)((c[q] >> 17) + 1));
            sx = fmaf(ww, bflo(v[q]), sx); sy = fmaf(ww, bfhi(v[q]), sy);
        }
    }
    for (; j + 4 <= e; j += 4) {
        unsigned c[4], v[4];
        #pragma unroll
        for (int q = 0; q < 4; ++q) c[q] = csr[j + q];
        #pragma unroll
        for (int q = 0; q < 4; ++q) v[q] = hp[(size_t)(c[q] & 0x1FFFF) * 64 + lane];
        #pragma unroll
        for (int q = 0; q < 4; ++q) {
            float ww = rsqrtf(dnf * (float)((c[q] >> 17) + 1));
            sx = fmaf(ww, bflo(v[q]), sx); sy = fmaf(ww, bfhi(v[q]), sy);
        }
    }
    for (; j < e; ++j) {
        unsigned c = csr[j];
        unsigned v = hp[(size_t)(c & 0x1FFFF) * 64 + lane];
        float ww = rsqrtf(dnf * (float)((c >> 17) + 1));
        sx = fmaf(ww, bflo(v), sx); sy = fmaf(ww, bfhi(v), sy);
    }
    float2 bb = ((const float2*)b1)[lane];
    aggb[base] = cvtpk(sx + bb.x, sy + bb.y);
}

// ---------------- BN stats (from bf16 agg) ----------------

__global__ __launch_bounds__(256) void k_bnstats(const unsigned* __restrict__ aggb,
                                                 float* __restrict__ bnsum, float* __restrict__ bnsumsq) {
    __shared__ float4 ss[256], sq[256];
    int g = threadIdx.x & 31;          // 4-channel group: channels 4g..4g+3
    int h = threadIdx.x >> 5;          // 0..7 row offset
    float4 fs = make_float4(0.f, 0.f, 0.f, 0.f);
    float4 fq = make_float4(0.f, 0.f, 0.f, 0.f);
    int rows_per_block = (NN + gridDim.x - 1) / gridDim.x;
    int r0 = blockIdx.x * rows_per_block;
    int r1 = r0 + rows_per_block; if (r1 > NN) r1 = NN;
    for (int r = r0 + h; r < r1; r += 8) {
        uint2 u = *(const uint2*)(aggb + (size_t)r * 64 + 2 * g);
        float a0 = bflo(u.x), a1 = bfhi(u.x), a2 = bflo(u.y), a3 = bfhi(u.y);
        fs.x += a0; fs.y += a1; fs.z += a2; fs.w += a3;
        fq.x += a0 * a0; fq.y += a1 * a1; fq.z += a2 * a2; fq.w += a3 * a3;
    }
    ss[threadIdx.x] = fs; sq[threadIdx.x] = fq;
    __syncthreads();
    if (threadIdx.x < 32) {
        float4 as = ss[threadIdx.x], aq = sq[threadIdx.x];
        #pragma unroll
        for (int k = 1; k < 8; ++k) {
            float4 bs = ss[k * 32 + threadIdx.x], bq = sq[k * 32 + threadIdx.x];
            as.x += bs.x; as.y += bs.y; as.z += bs.z; as.w += bs.w;
            aq.x += bq.x; aq.y += bq.y; aq.z += bq.z; aq.w += bq.w;
        }
        atomicAdd(&bnsum[4 * g + 0], as.x); atomicAdd(&bnsum[4 * g + 1], as.y);
        atomicAdd(&bnsum[4 * g + 2], as.z); atomicAdd(&bnsum[4 * g + 3], as.w);
        atomicAdd(&bnsumsq[4 * g + 0], aq.x); atomicAdd(&bnsumsq[4 * g + 1], aq.y);
        atomicAdd(&bnsumsq[4 * g + 2], aq.z); atomicAdd(&bnsumsq[4 * g + 3], aq.w);
    }
}

// ---------------- GEMM2 (+inline BN finalize): h2b = relu(bn(aggb)) @ W2 ----------------

__global__ __launch_bounds__(256) void k_gemm2(const unsigned* __restrict__ aggb, const float* __restrict__ W2,
                                               const float* __restrict__ bnsum, const float* __restrict__ bnsumsq,
                                               const float* __restrict__ gamma, const float* __restrict__ beta,
                                               unsigned short* __restrict__ h2b) {
    __shared__ float As2[32][66];
    __shared__ float Bs2[32][OUTC];
    __shared__ float bnsc[HID], bnsh[HID];
    int tid = threadIdx.x;
    if (tid < HID) {
        float mu = bnsum[tid] / (float)NN;
        float var = bnsumsq[tid] / (float)NN - mu * mu;
        float sc = gamma[tid] * rsqrtf(var + BN_EPS);
        bnsc[tid] = sc;
        bnsh[tid] = beta[tid] - mu * sc;
    }
    __syncthreads();
    int m0 = blockIdx.x * 64;
    int tx = tid & 15, ty = tid >> 4;
    float acc[4][4];
    #pragma unroll
    for (int r = 0; r < 4; ++r)
        #pragma unroll
        for (int c = 0; c < 4; ++c) acc[r][c] = 0.f;

    int am = tid >> 3;          // 0..31
    int ak = (tid & 7) * 4;     // 0..28
    int bk = tid >> 4;          // 0..15
    int bc = (tid & 15) * 4;    // 0..60

    for (int k0 = 0; k0 < HID; k0 += 32) {
        #pragma unroll
        for (int h = 0; h < 2; ++h) {
            int m = am + h * 32;
            int rowi = m0 + m; if (rowi >= NN) rowi = NN - 1;
            uint2 u = *(const uint2*)(aggb + (size_t)rowi * 64 + ((k0 + ak) >> 1));
            float4 sc = *(const float4*)&bnsc[k0 + ak];
            float4 sh = *(const float4*)&bnsh[k0 + ak];
            As2[ak + 0][m] = fmaxf(fmaf(bflo(u.x), sc.x, sh.x), 0.f);
            As2[ak + 1][m] = fmaxf(fmaf(bfhi(u.x), sc.y, sh.y), 0.f);
            As2[ak + 2][m] = fmaxf(fmaf(bflo(u.y), sc.z, sh.z), 0.f);
            As2[ak + 3][m] = fmaxf(fmaf(bfhi(u.y), sc.w, sh.w), 0.f);
        }
        #pragma unroll
        for (int h = 0; h < 2; ++h) {
            int k = bk + h * 16;
            *(float4*)&Bs2[k][bc] = *(const float4*)(W2 + (size_t)(k0 + k) * OUTC + bc);
        }
        __syncthreads();
        #pragma unroll
        for (int k = 0; k < 32; ++k) {
            float a[4];
            #pragma unroll
            for (int r = 0; r < 4; ++r) a[r] = As2[k][ty * 4 + r];
            float4 b = *(const float4*)&Bs2[k][tx * 4];
            #pragma unroll
            for (int r = 0; r < 4; ++r) {
                acc[r][0] = fmaf(a[r], b.x, acc[r][0]);
                acc[r][1] = fmaf(a[r], b.y, acc[r][1]);
                acc[r][2] = fmaf(a[r], b.z, acc[r][2]);
                acc[r][3] = fmaf(a[r], b.w, acc[r][3]);
            }
        }
        __syncthreads();
    }
    #pragma unroll
    for (int r = 0; r < 4; ++r) {
        int m = m0 + ty * 4 + r;
        if (m < NN) {
            *(uint2*)(h2b + (size_t)m * OUTC + tx * 4) =
                make_uint2(cvtpk(acc[r][0], acc[r][1]), cvtpk(acc[r][2], acc[r][3]));
        }
    }
}

// ---------------- aggregation 2 (64 ch bf16): 1 wave/node, lane-halves alternate edges ----------------

__global__ __launch_bounds__(256) void k_agg2(const unsigned short* __restrict__ h2b,
                                              const int* __restrict__ rowptr, const unsigned* __restrict__ csr,
                                              const float* __restrict__ b2, float* __restrict__ out) {
    int node = blockIdx.x * 4 + (threadIdx.x >> 6);
    int lane = threadIdx.x & 63;
    int l32 = lane & 31;
    const unsigned* hp = (const unsigned*)h2b;     // 32 uints per row (2 bf16 ch each)
    int s = rowptr[node], e = rowptr[node + 1];
    float dnf = (float)(e - s + 1);
    float di = rsqrtf(dnf);
    float wself = di * di;
    float sx = 0.f, sy = 0.f;
    if (lane < 32) {
        unsigned u = hp[(size_t)node * 32 + l32];
        sx = wself * bflo(u);
        sy = wself * bfhi(u);
    }
    int j = s + (lane >> 5);
    for (; j + 14 < e; j += 16) {
        unsigned c[8], v[8];
        #pragma unroll
        for (int q = 0; q < 8; ++q) c[q] = csr[j + 2 * q];
        #pragma unroll
        for (int q = 0; q < 8; ++q) v[q] = hp[(size_t)(c[q] & 0x1FFFF) * 32 + l32];
        #pragma unroll
        for (int q = 0; q < 8; ++q) {
            float ww = rsqrtf(dnf * (float)((c[q] >> 17) + 1));
            sx = fmaf(ww, bflo(v[q]), sx); sy = fmaf(ww, bfhi(v[q]), sy);
        }
    }
    for (; j + 2 < e; j += 4) {
        unsigned c0 = csr[j], c1 = csr[j + 2];
        unsigned v0 = hp[(size_t)(c0 & 0x1FFFF) * 32 + l32];
        unsigned v1 = hp[(size_t)(c1 & 0x1FFFF) * 32 + l32];
        float w0 = rsqrtf(dnf * (float)((c0 >> 17) + 1));
        float w1 = rsqrtf(dnf * (float)((c1 >> 17) + 1));
        sx = fmaf(w0, bflo(v0), sx); sy = fmaf(w0, bfhi(v0), sy);
        sx = fmaf(w1, bflo(v1), sx); sy = fmaf(w1, bfhi(v1), sy);
    }
    if (j < e) {
        unsigned c = csr[j];
        unsigned v = hp[(size_t)(c & 0x1FFFF) * 32 + l32];
        float ww = rsqrtf(dnf * (float)((c >> 17) + 1));
        sx = fmaf(ww, bflo(v), sx); sy = fmaf(ww, bfhi(v), sy);
    }
    sx += __shfl_xor(sx, 32);
    sy += __shfl_xor(sy, 32);
    if (lane < 32) {
        float2 bb = ((const float2*)b2)[l32];
        ((float2*)out)[(size_t)node * 32 + l32] = make_float2(sx + bb.x, sy + bb.y);
    }
}

// ---------------- launch ----------------

extern "C" void kernel_launch(void* const* d_in, const int* in_sizes, int n_in,
                              void* d_out, int out_size, void* d_ws, size_t ws_size,
                              hipStream_t stream) {
    const float* x     = (const float*)d_in[0];
    const int*   ei    = (const int*)d_in[1];
    const float* W1    = (const float*)d_in[2];
    const float* b1    = (const float*)d_in[3];
    const float* gamma = (const float*)d_in[4];
    const float* beta  = (const float*)d_in[5];
    const float* W2    = (const float*)d_in[6];
    const float* b2    = (const float*)d_in[7];
    const int* row = ei;          // edge_index[0]
    const int* col = ei + NE;     // edge_index[1]
    float* out = (float*)d_out;

    char* wp = (char*)d_ws;
    auto alloc = [&](size_t bytes) -> void* {
        void* p = (void*)wp;
        wp += (bytes + 255) & ~(size_t)255;
        return p;
    };
    unsigned short* h1b = (unsigned short*)alloc((size_t)NN * HID * 2);
    unsigned* aggb = (unsigned*)alloc((size_t)NN * HID * 2);
    unsigned short* h2b = (unsigned short*)alloc((size_t)NN * OUTC * 2);
    int*   deg     = (int*)alloc((size_t)NN * 4);
    float* bnsum   = (float*)alloc(HID * 4);
    float* bnsumsq = (float*)alloc(HID * 4);
    int*   rowptr  = (int*)alloc((size_t)(NN + 1) * 4);
    int*   bhist   = (int*)alloc((size_t)NBUK * NBLK * 4);
    int*   bsum2   = (int*)alloc(NSCB * 4);
    unsigned* ebuk = (unsigned*)alloc((size_t)NE * 4);
    unsigned* csr  = (unsigned*)alloc((size_t)NE * 4);
    unsigned short* W1T = (unsigned short*)alloc((size_t)HID * INC * 2);

    hipLaunchKernelGGL(k_pre,    dim3(NBLK), dim3(256), 0, stream, col, bhist, W1, W1T, bnsum, bnsumsq);
    hipLaunchKernelGGL(k_gscanA, dim3(NSCB), dim3(GS_B), 0, stream, bhist, bhist, bsum2, NBUK * NBLK);
    hipLaunchKernelGGL(k_fuse1,  dim3(NBLK + G1A), dim3(256), 0, stream, row, col, bhist, bsum2, ebuk, x, W1T, h1b);
    hipLaunchKernelGGL(k_fuse2,  dim3(NBUK + G1B), dim3(256), 0, stream, ebuk, bhist, bsum2, deg, rowptr, x, W1T, h1b);
    hipLaunchKernelGGL(k_fuse3,  dim3(NBUK + G1C), dim3(256), 0, stream, ebuk, bhist, bsum2, rowptr, deg, csr, x, W1T, h1b);
    hipLaunchKernelGGL(k_agg1,   dim3(NN / 4), dim3(256), 0, stream, h1b, rowptr, csr, b1, aggb);
    hipLaunchKernelGGL(k_bnstats, dim3(256), dim3(256), 0, stream, aggb, bnsum, bnsumsq);
    hipLaunchKernelGGL(k_gemm2,  dim3((NN + 63) / 64), dim3(256), 0, stream, aggb, W2, bnsum, bnsumsq, gamma, beta, h2b);
    hipLaunchKernelGGL(k_agg2,   dim3(NN / 4), dim3(256), 0, stream, h2b, rowptr, csr, b2, out);
}

// Round 11
// 311.294 us; speedup vs baseline: 1.1012x; 1.0438x over previous
//
#include <hip/hip_runtime.h>

#define NN 100000
#define NE 1600000
#define INC 512
#define HID 128
#define OUTC 64
#define BN_EPS 1e-5f

#define GS_B 1024
#define NSCB 98                   // scan blocks for NBUK*NBLK (=100096 <= 100352)

#define NBLK 256
#define CHUNK (NE / NBLK)         // 6250 exactly
#define BSH 8
#define NBUK ((NN + 255) >> 8)    // 391 buckets of 256 nodes

#define G1_TOTAL 1563             // ceil(NN/64)
#define G1A 704
#define G1B 288
#define G1C 571                   // 704+288+571 = 1563

#define APAD 72                   // LDS row stride in shorts (144B -> 2-way alias, free)
#define SMEM_BYTES (64 * APAD * 2 + 128 * APAD * 2)   // 27648: gemm1 As+Bs

typedef __attribute__((ext_vector_type(8))) short short8v;
typedef __attribute__((ext_vector_type(4))) float f32x4;

__device__ __forceinline__ unsigned short f2bf(float f) {
    unsigned u = __float_as_uint(f);
    u += 0x7FFFu + ((u >> 16) & 1u);     // round-to-nearest-even
    return (unsigned short)(u >> 16);
}

// packed f32x2 -> bf16x2 (RNE), D[15:0]=bf16(lo), D[31:16]=bf16(hi)
__device__ __forceinline__ unsigned cvtpk(float lo, float hi) {
    unsigned r;
    asm("v_cvt_pk_bf16_f32 %0, %1, %2" : "=v"(r) : "v"(lo), "v"(hi));
    return r;
}

__device__ __forceinline__ float bflo(unsigned u) { return __uint_as_float(u << 16); }
__device__ __forceinline__ float bfhi(unsigned u) { return __uint_as_float(u & 0xFFFF0000u); }

// scan the 98 raw block totals into an exclusive prefix, in LDS (per-block redundant)
__device__ __forceinline__ void scan_bsum(const int* __restrict__ bsum2, int* spref) {
    int tid = threadIdx.x;
    if (tid < NSCB) spref[tid] = bsum2[tid];
    __syncthreads();
    if (tid == 0) {
        int run = 0;
        #pragma unroll 1
        for (int i = 0; i < NSCB; ++i) { int t = spref[i]; spref[i] = run; run += t; }
    }
    __syncthreads();
}

// ---------------- fused: W1->bf16T + bucket histogram + BN-acc zero ----------------

__global__ __launch_bounds__(256) void k_pre(const int* __restrict__ col, int* __restrict__ bhist,
                                             const float* __restrict__ W1, unsigned short* __restrict__ W1T,
                                             float* bnsum, float* bnsumsq) {
    __shared__ int lc[NBUK];
    int tid = threadIdx.x, blk = blockIdx.x;
    int i = blk * 256 + tid;                     // 65536 W1 elements, grid is exactly 256 blocks
    W1T[(size_t)(i & 127) * INC + (i >> 7)] = f2bf(W1[i]);
    if (blk == 0 && tid < HID) { bnsum[tid] = 0.f; bnsumsq[tid] = 0.f; }
    for (int q = tid; q < NBUK; q += 256) lc[q] = 0;
    __syncthreads();
    int s = blk * CHUNK, e = s + CHUNK;
    for (int j = s + tid; j < e; j += 256)
        atomicAdd(&lc[col[j] >> BSH], 1);
    __syncthreads();
    for (int q = tid; q < NBUK; q += 256)
        bhist[q * NBLK + blk] = lc[q];
}

// generic scan: per-block exclusive prefix (in-place safe) + raw block totals
__global__ void k_gscanA(const int* __restrict__ src, int* __restrict__ dst,
                         int* __restrict__ bsum, int n) {
    __shared__ int s[GS_B];
    int tid = threadIdx.x;
    int i = blockIdx.x * GS_B + tid;
    int v = (i < n) ? src[i] : 0;
    s[tid] = v;
    __syncthreads();
    for (int off = 1; off < GS_B; off <<= 1) {
        int t = (tid >= off) ? s[tid - off] : 0;
        __syncthreads();
        s[tid] += t;
        __syncthreads();
    }
    if (i < n) dst[i] = s[tid] - v;
    if (tid == GS_B - 1) bsum[blockIdx.x] = s[tid];
}

// ---------------- device bodies for the fat kernels ----------------

// partition edges into buckets; entry = row | (local_col << 24)
__device__ void dev_bpart(char* smem, const int* __restrict__ row, const int* __restrict__ col,
                          const int* __restrict__ sb, const int* __restrict__ bsum2,
                          unsigned* __restrict__ ebuk, int blk) {
    int* lcur = (int*)smem;                       // NBUK ints
    int* spref = (int*)(smem + ((NBUK * 4 + 15) & ~15));  // NSCB ints
    int tid = threadIdx.x;
    scan_bsum(bsum2, spref);
    for (int i = tid; i < NBUK; i += 256) {
        int idx = i * NBLK + blk;
        lcur[i] = sb[idx] + spref[idx >> 10];
    }
    __syncthreads();
    int s = blk * CHUNK, e = s + CHUNK;
    for (int j = s + tid; j < e; j += 256) {
        int r = row[j], c = col[j];
        int p = atomicAdd(&lcur[c >> BSH], 1);
        ebuk[p] = (unsigned)r | ((unsigned)(c & 255) << 24);
    }
}

// per-bucket: node counts -> deg[], local exclusive scan -> rowptr[]
__device__ void dev_nprep(char* smem, const unsigned* __restrict__ ebuk,
                          const int* __restrict__ sb, const int* __restrict__ bsum2,
                          int* __restrict__ deg, int* __restrict__ rowptr, int b) {
    int* lc = (int*)smem;                         // 256
    int* sc = (int*)(smem + 1024);                // 256
    int* spref = (int*)(smem + 2048);             // NSCB
    int tid = threadIdx.x;
    scan_bsum(bsum2, spref);
    lc[tid] = 0;
    __syncthreads();
    int i0 = b * NBLK;
    int s = sb[i0] + spref[i0 >> 10];
    int e2 = (b + 1 < NBUK) ? (sb[i0 + NBLK] + spref[(i0 + NBLK) >> 10]) : NE;
    for (int j = s + tid; j < e2; j += 256)
        atomicAdd(&lc[ebuk[j] >> 24], 1);
    __syncthreads();
    int v = lc[tid];
    sc[tid] = v;
    __syncthreads();
    for (int off = 1; off < 256; off <<= 1) {
        int t = (tid >= off) ? sc[tid - off] : 0;
        __syncthreads();
        sc[tid] += t;
        __syncthreads();
    }
    int node = (b << BSH) + tid;
    if (node < NN) {
        deg[node] = v;
        rowptr[node] = s + sc[tid] - v;
    }
    if (b == NBUK - 1 && tid == 0) rowptr[NN] = NE;
}

// scatter csr entries: entry = row | (deg[row] << 17)
__device__ void dev_bfill(char* smem, const unsigned* __restrict__ ebuk,
                          const int* __restrict__ sb, const int* __restrict__ bsum2,
                          const int* __restrict__ rowptr, const int* __restrict__ deg,
                          unsigned* __restrict__ csr, int b) {
    int* lcur = (int*)smem;                       // 256
    int* spref = (int*)(smem + 1024);             // NSCB
    int tid = threadIdx.x;
    scan_bsum(bsum2, spref);
    int node0 = b << BSH;
    int node = node0 + tid;
    lcur[tid] = (node < NN) ? rowptr[node] : 0;
    __syncthreads();
    int i0 = b * NBLK;
    int s = sb[i0] + spref[i0 >> 10];
    int e2 = (b + 1 < NBUK) ? (sb[i0 + NBLK] + spref[(i0 + NBLK) >> 10]) : NE;
    for (int j = s + tid; j < e2; j += 256) {
        unsigned rc = ebuk[j];
        int li = rc >> 24;
        int r = rc & 0xFFFFFF;
        int p = atomicAdd(&lcur[li], 1);
        csr[p] = (unsigned)r | ((unsigned)deg[r] << 17);
    }
}

// GEMM1 (MFMA) block body: 64 rows x 128 cols per block, 4 waves, BK=64.
// register-prefetch double-stage; operands swapped so lane owns 4 consecutive channels.
#define G1BK 64

__device__ void dev_gemm1(char* smem, const float* __restrict__ x,
                          const unsigned short* __restrict__ W1T,
                          unsigned short* __restrict__ h1b, int mblk) {
    unsigned short (*As)[APAD] = (unsigned short (*)[APAD])smem;
    unsigned short (*Bs)[APAD] = (unsigned short (*)[APAD])(smem + 64 * APAD * 2);
    int tid = threadIdx.x;
    int m0 = mblk * 64;
    int w = tid >> 6;
    int lane = tid & 63;

    f32x4 acc[4][2];
    #pragma unroll
    for (int mr = 0; mr < 4; ++mr)
        #pragma unroll
        for (int cb = 0; cb < 2; ++cb) acc[mr][cb] = (f32x4){0.f, 0.f, 0.f, 0.f};

    int ar = tid >> 2;
    int ak = (tid & 3) * 16;
    int arow = m0 + ar; if (arow >= NN) arow = NN - 1;
    const float* xr = x + (size_t)arow * INC;
    int br = tid >> 1;
    int bk = (tid & 1) * 32;
    const unsigned short* wr = W1T + (size_t)br * INC;

    int frow = lane & 15;
    int fk = (lane >> 4) * 8;

    float4 pv[4];
    short8v pb[4];
    #pragma unroll
    for (int q = 0; q < 4; ++q) pv[q] = *(const float4*)(xr + ak + q * 4);
    #pragma unroll
    for (int q = 0; q < 4; ++q) pb[q] = *(const short8v*)(wr + bk + q * 8);

    for (int k0 = 0; k0 < INC; k0 += G1BK) {
        #pragma unroll
        for (int q = 0; q < 4; ++q)
            *(uint2*)&As[ar][ak + q * 4] = make_uint2(cvtpk(pv[q].x, pv[q].y), cvtpk(pv[q].z, pv[q].w));
        #pragma unroll
        for (int q = 0; q < 4; ++q)
            *(short8v*)&Bs[br][bk + q * 8] = pb[q];
        __syncthreads();
        if (k0 + G1BK < INC) {
            #pragma unroll
            for (int q = 0; q < 4; ++q) pv[q] = *(const float4*)(xr + k0 + G1BK + ak + q * 4);
            #pragma unroll
            for (int q = 0; q < 4; ++q) pb[q] = *(const short8v*)(wr + k0 + G1BK + bk + q * 8);
        }
        #pragma unroll
        for (int kk = 0; kk < G1BK; kk += 32) {
            short8v a[4], b[2];
            #pragma unroll
            for (int mr = 0; mr < 4; ++mr)
                a[mr] = *(const short8v*)&As[16 * mr + frow][kk + fk];   // x nodes (B operand)
            #pragma unroll
            for (int cb = 0; cb < 2; ++cb)
                b[cb] = *(const short8v*)&Bs[32 * w + 16 * cb + frow][kk + fk];  // W channels (A operand)
            #pragma unroll
            for (int mr = 0; mr < 4; ++mr)
                #pragma unroll
                for (int cb = 0; cb < 2; ++cb)
                    acc[mr][cb] = __builtin_amdgcn_mfma_f32_16x16x32_bf16(b[cb], a[mr], acc[mr][cb], 0, 0, 0);
        }
        __syncthreads();
    }
    int ncol = lane & 15;
    int r4 = (lane >> 4) * 4;
    #pragma unroll
    for (int mr = 0; mr < 4; ++mr) {
        int node = m0 + 16 * mr + ncol;
        if (node < NN) {
            #pragma unroll
            for (int cb = 0; cb < 2; ++cb) {
                int ch = 32 * w + 16 * cb + r4;
                *(uint2*)&h1b[(size_t)node * HID + ch] =
                    make_uint2(cvtpk(acc[mr][cb][0], acc[mr][cb][1]),
                               cvtpk(acc[mr][cb][2], acc[mr][cb][3]));
            }
        }
    }
}

// ---------------- fat kernels: CSR stage + gemm1 slice ----------------

__global__ __launch_bounds__(256) void k_fuse1(const int* __restrict__ row, const int* __restrict__ col,
                                               const int* __restrict__ sb, const int* __restrict__ bsum2,
                                               unsigned* __restrict__ ebuk,
                                               const float* __restrict__ x,
                                               const unsigned short* __restrict__ W1T,
                                               unsigned short* __restrict__ h1b) {
    __shared__ __align__(16) char smem[SMEM_BYTES];
    if (blockIdx.x < NBLK) dev_bpart(smem, row, col, sb, bsum2, ebuk, blockIdx.x);
    else                   dev_gemm1(smem, x, W1T, h1b, blockIdx.x - NBLK);
}

__global__ __launch_bounds__(256) void k_fuse2(const unsigned* __restrict__ ebuk,
                                               const int* __restrict__ sb, const int* __restrict__ bsum2,
                                               int* __restrict__ deg, int* __restrict__ rowptr,
                                               const float* __restrict__ x,
                                               const unsigned short* __restrict__ W1T,
                                               unsigned short* __restrict__ h1b) {
    __shared__ __align__(16) char smem[SMEM_BYTES];
    if (blockIdx.x < NBUK) dev_nprep(smem, ebuk, sb, bsum2, deg, rowptr, blockIdx.x);
    else                   dev_gemm1(smem, x, W1T, h1b, blockIdx.x - NBUK + G1A);
}

__global__ __launch_bounds__(256) void k_fuse3(const unsigned* __restrict__ ebuk,
                                               const int* __restrict__ sb, const int* __restrict__ bsum2,
                                               const int* __restrict__ rowptr, const int* __restrict__ deg,
                                               unsigned* __restrict__ csr,
                                               const float* __restrict__ x,
                                               const unsigned short* __restrict__ W1T,
                                               unsigned short* __restrict__ h1b) {
    __shared__ __align__(16) char smem[SMEM_BYTES];
    if (blockIdx.x < NBUK) dev_bfill(smem, ebuk, sb, bsum2, rowptr, deg, csr, blockIdx.x);
    else                   dev_gemm1(smem, x, W1T, h1b, blockIdx.x - NBUK + G1A + G1B);
}

// ---------------- aggregation 1 (128 ch bf16 -> bf16): 1 wave/node, 8-deep unroll ----------------

__global__ __launch_bounds__(256) void k_agg1(const unsigned short* __restrict__ h1b,
                                              const int* __restrict__ rowptr, const unsigned* __restrict__ csr,
                                              const float* __restrict__ b1, unsigned* __restrict__ aggb) {
    int node = blockIdx.x * 4 + (threadIdx.x >> 6);
    int lane = threadIdx.x & 63;
    const unsigned* hp = (const unsigned*)h1b;     // 64 uints per row (2 bf16 ch each)
    size_t base = (size_t)node * 64 + lane;
    int s = rowptr[node], e = rowptr[node + 1];
    float dnf = (float)(e - s + 1);
    float di = rsqrtf(dnf);
    float wself = di * di;
    unsigned hv = hp[base];
    float sx = wself * bflo(hv);
    float sy = wself * bfhi(hv);
    int j = s;
    for (; j + 8 <= e; j += 8) {
        unsigned c[8], v[8];
        #pragma unroll
        for (int q = 0; q < 8; ++q) c[q] = csr[j + q];
        #pragma unroll
        for (int q = 0; q < 8; ++q) v[q] = hp[(size_t)(c[q] & 0x1FFFF) * 64 + lane];
        #pragma unroll
        for (int q = 0; q < 8; ++q) {
            float ww = rsqrtf(dnf * (float)((c[q] >> 17) + 1));
            sx = fmaf(ww, bflo(v[q]), sx); sy = fmaf(ww, bfhi(v[q]), sy);
        }
    }
    for (; j + 4 <= e; j += 4) {
        unsigned c[4], v[4];
        #pragma unroll
        for (int q = 0; q < 4; ++q) c[q] = csr[j + q];
        #pragma unroll
        for (int q = 0; q < 4; ++q) v[q] = hp[(size_t)(c[q] & 0x1FFFF) * 64 + lane];
        #pragma unroll
        for (int q = 0; q < 4; ++q) {
            float ww = rsqrtf(dnf * (float)((c[q] >> 17) + 1));
            sx = fmaf(ww, bflo(v[q]), sx); sy = fmaf(ww, bfhi(v[q]), sy);
        }
    }
    for (; j < e; ++j) {
        unsigned c = csr[j];
        unsigned v = hp[(size_t)(c & 0x1FFFF) * 64 + lane];
        float ww = rsqrtf(dnf * (float)((c >> 17) + 1));
        sx = fmaf(ww, bflo(v), sx); sy = fmaf(ww, bfhi(v), sy);
    }
    float2 bb = ((const float2*)b1)[lane];
    aggb[base] = cvtpk(sx + bb.x, sy + bb.y);
}

// ---------------- BN stats (from bf16 agg) ----------------

__global__ __launch_bounds__(256) void k_bnstats(const unsigned* __restrict__ aggb,
                                                 float* __restrict__ bnsum, float* __restrict__ bnsumsq) {
    __shared__ float4 ss[256], sq[256];
    int g = threadIdx.x & 31;          // 4-channel group: channels 4g..4g+3
    int h = threadIdx.x >> 5;          // 0..7 row offset
    float4 fs = make_float4(0.f, 0.f, 0.f, 0.f);
    float4 fq = make_float4(0.f, 0.f, 0.f, 0.f);
    int rows_per_block = (NN + gridDim.x - 1) / gridDim.x;
    int r0 = blockIdx.x * rows_per_block;
    int r1 = r0 + rows_per_block; if (r1 > NN) r1 = NN;
    for (int r = r0 + h; r < r1; r += 8) {
        uint2 u = *(const uint2*)(aggb + (size_t)r * 64 + 2 * g);
        float a0 = bflo(u.x), a1 = bfhi(u.x), a2 = bflo(u.y), a3 = bfhi(u.y);
        fs.x += a0; fs.y += a1; fs.z += a2; fs.w += a3;
        fq.x += a0 * a0; fq.y += a1 * a1; fq.z += a2 * a2; fq.w += a3 * a3;
    }
    ss[threadIdx.x] = fs; sq[threadIdx.x] = fq;
    __syncthreads();
    if (threadIdx.x < 32) {
        float4 as = ss[threadIdx.x], aq = sq[threadIdx.x];
        #pragma unroll
        for (int k = 1; k < 8; ++k) {
            float4 bs = ss[k * 32 + threadIdx.x], bq = sq[k * 32 + threadIdx.x];
            as.x += bs.x; as.y += bs.y; as.z += bs.z; as.w += bs.w;
            aq.x += bq.x; aq.y += bq.y; aq.z += bq.z; aq.w += bq.w;
        }
        atomicAdd(&bnsum[4 * g + 0], as.x); atomicAdd(&bnsum[4 * g + 1], as.y);
        atomicAdd(&bnsum[4 * g + 2], as.z); atomicAdd(&bnsum[4 * g + 3], as.w);
        atomicAdd(&bnsumsq[4 * g + 0], aq.x); atomicAdd(&bnsumsq[4 * g + 1], aq.y);
        atomicAdd(&bnsumsq[4 * g + 2], aq.z); atomicAdd(&bnsumsq[4 * g + 3], aq.w);
    }
}

// ---------------- GEMM2 (+inline BN finalize): h2b = relu(bn(aggb)) @ W2 ----------------

__global__ __launch_bounds__(256) void k_gemm2(const unsigned* __restrict__ aggb, const float* __restrict__ W2,
                                               const float* __restrict__ bnsum, const float* __restrict__ bnsumsq,
                                               const float* __restrict__ gamma, const float* __restrict__ beta,
                                               unsigned short* __restrict__ h2b) {
    __shared__ float As2[32][66];
    __shared__ float Bs2[32][OUTC];
    __shared__ float bnsc[HID], bnsh[HID];
    int tid = threadIdx.x;
    if (tid < HID) {
        float mu = bnsum[tid] / (float)NN;
        float var = bnsumsq[tid] / (float)NN - mu * mu;
        float sc = gamma[tid] * rsqrtf(var + BN_EPS);
        bnsc[tid] = sc;
        bnsh[tid] = beta[tid] - mu * sc;
    }
    __syncthreads();
    int m0 = blockIdx.x * 64;
    int tx = tid & 15, ty = tid >> 4;
    float acc[4][4];
    #pragma unroll
    for (int r = 0; r < 4; ++r)
        #pragma unroll
        for (int c = 0; c < 4; ++c) acc[r][c] = 0.f;

    int am = tid >> 3;          // 0..31
    int ak = (tid & 7) * 4;     // 0..28
    int bk = tid >> 4;          // 0..15
    int bc = (tid & 15) * 4;    // 0..60

    for (int k0 = 0; k0 < HID; k0 += 32) {
        #pragma unroll
        for (int h = 0; h < 2; ++h) {
            int m = am + h * 32;
            int rowi = m0 + m; if (rowi >= NN) rowi = NN - 1;
            uint2 u = *(const uint2*)(aggb + (size_t)rowi * 64 + ((k0 + ak) >> 1));
            float4 sc = *(const float4*)&bnsc[k0 + ak];
            float4 sh = *(const float4*)&bnsh[k0 + ak];
            As2[ak + 0][m] = fmaxf(fmaf(bflo(u.x), sc.x, sh.x), 0.f);
            As2[ak + 1][m] = fmaxf(fmaf(bfhi(u.x), sc.y, sh.y), 0.f);
            As2[ak + 2][m] = fmaxf(fmaf(bflo(u.y), sc.z, sh.z), 0.f);
            As2[ak + 3][m] = fmaxf(fmaf(bfhi(u.y), sc.w, sh.w), 0.f);
        }
        #pragma unroll
        for (int h = 0; h < 2; ++h) {
            int k = bk + h * 16;
            *(float4*)&Bs2[k][bc] = *(const float4*)(W2 + (size_t)(k0 + k) * OUTC + bc);
        }
        __syncthreads();
        #pragma unroll
        for (int k = 0; k < 32; ++k) {
            float a[4];
            #pragma unroll
            for (int r = 0; r < 4; ++r) a[r] = As2[k][ty * 4 + r];
            float4 b = *(const float4*)&Bs2[k][tx * 4];
            #pragma unroll
            for (int r = 0; r < 4; ++r) {
                acc[r][0] = fmaf(a[r], b.x, acc[r][0]);
                acc[r][1] = fmaf(a[r], b.y, acc[r][1]);
                acc[r][2] = fmaf(a[r], b.z, acc[r][2]);
                acc[r][3] = fmaf(a[r], b.w, acc[r][3]);
            }
        }
        __syncthreads();
    }
    #pragma unroll
    for (int r = 0; r < 4; ++r) {
        int m = m0 + ty * 4 + r;
        if (m < NN) {
            *(uint2*)(h2b + (size_t)m * OUTC + tx * 4) =
                make_uint2(cvtpk(acc[r][0], acc[r][1]), cvtpk(acc[r][2], acc[r][3]));
        }
    }
}

// ---------------- aggregation 2 (64 ch bf16): 1 wave/node, lane-halves alternate edges ----------------

__global__ __launch_bounds__(256) void k_agg2(const unsigned short* __restrict__ h2b,
                                              const int* __restrict__ rowptr, const unsigned* __restrict__ csr,
                                              const float* __restrict__ b2, float* __restrict__ out) {
    int node = blockIdx.x * 4 + (threadIdx.x >> 6);
    int lane = threadIdx.x & 63;
    int l32 = lane & 31;
    const unsigned* hp = (const unsigned*)h2b;     // 32 uints per row (2 bf16 ch each)
    int s = rowptr[node], e = rowptr[node + 1];
    float dnf = (float)(e - s + 1);
    float di = rsqrtf(dnf);
    float wself = di * di;
    float sx = 0.f, sy = 0.f;
    if (lane < 32) {
        unsigned u = hp[(size_t)node * 32 + l32];
        sx = wself * bflo(u);
        sy = wself * bfhi(u);
    }
    int j = s + (lane >> 5);
    for (; j + 6 < e; j += 8) {
        unsigned c0 = csr[j], c1 = csr[j + 2], c2 = csr[j + 4], c3 = csr[j + 6];
        unsigned v0 = hp[(size_t)(c0 & 0x1FFFF) * 32 + l32];
        unsigned v1 = hp[(size_t)(c1 & 0x1FFFF) * 32 + l32];
        unsigned v2 = hp[(size_t)(c2 & 0x1FFFF) * 32 + l32];
        unsigned v3 = hp[(size_t)(c3 & 0x1FFFF) * 32 + l32];
        float w0 = rsqrtf(dnf * (float)((c0 >> 17) + 1));
        float w1 = rsqrtf(dnf * (float)((c1 >> 17) + 1));
        float w2 = rsqrtf(dnf * (float)((c2 >> 17) + 1));
        float w3 = rsqrtf(dnf * (float)((c3 >> 17) + 1));
        sx = fmaf(w0, bflo(v0), sx); sy = fmaf(w0, bfhi(v0), sy);
        sx = fmaf(w1, bflo(v1), sx); sy = fmaf(w1, bfhi(v1), sy);
        sx = fmaf(w2, bflo(v2), sx); sy = fmaf(w2, bfhi(v2), sy);
        sx = fmaf(w3, bflo(v3), sx); sy = fmaf(w3, bfhi(v3), sy);
    }
    for (; j + 2 < e; j += 4) {
        unsigned c0 = csr[j], c1 = csr[j + 2];
        unsigned v0 = hp[(size_t)(c0 & 0x1FFFF) * 32 + l32];
        unsigned v1 = hp[(size_t)(c1 & 0x1FFFF) * 32 + l32];
        float w0 = rsqrtf(dnf * (float)((c0 >> 17) + 1));
        float w1 = rsqrtf(dnf * (float)((c1 >> 17) + 1));
        sx = fmaf(w0, bflo(v0), sx); sy = fmaf(w0, bfhi(v0), sy);
        sx = fmaf(w1, bflo(v1), sx); sy = fmaf(w1, bfhi(v1), sy);
    }
    if (j < e) {
        unsigned c = csr[j];
        unsigned v = hp[(size_t)(c & 0x1FFFF) * 32 + l32];
        float ww = rsqrtf(dnf * (float)((c >> 17) + 1));
        sx = fmaf(ww, bflo(v), sx); sy = fmaf(ww, bfhi(v), sy);
    }
    sx += __shfl_xor(sx, 32);
    sy += __shfl_xor(sy, 32);
    if (lane < 32) {
        float2 bb = ((const float2*)b2)[l32];
        ((float2*)out)[(size_t)node * 32 + l32] = make_float2(sx + bb.x, sy + bb.y);
    }
}

// ---------------- launch ----------------

extern "C" void kernel_launch(void* const* d_in, const int* in_sizes, int n_in,
                              void* d_out, int out_size, void* d_ws, size_t ws_size,
                              hipStream_t stream) {
    const float* x     = (const float*)d_in[0];
    const int*   ei    = (const int*)d_in[1];
    const float* W1    = (const float*)d_in[2];
    const float* b1    = (const float*)d_in[3];
    const float* gamma = (const float*)d_in[4];
    const float* beta  = (const float*)d_in[5];
    const float* W2    = (const float*)d_in[6];
    const float* b2    = (const float*)d_in[7];
    const int* row = ei;          // edge_index[0]
    const int* col = ei + NE;     // edge_index[1]
    float* out = (float*)d_out;

    char* wp = (char*)d_ws;
    auto alloc = [&](size_t bytes) -> void* {
        void* p = (void*)wp;
        wp += (bytes + 255) & ~(size_t)255;
        return p;
    };
    unsigned short* h1b = (unsigned short*)alloc((size_t)NN * HID * 2);
    unsigned* aggb = (unsigned*)alloc((size_t)NN * HID * 2);
    unsigned short* h2b = (unsigned short*)alloc((size_t)NN * OUTC * 2);
    int*   deg     = (int*)alloc((size_t)NN * 4);
    float* bnsum   = (float*)alloc(HID * 4);
    float* bnsumsq = (float*)alloc(HID * 4);
    int*   rowptr  = (int*)alloc((size_t)(NN + 1) * 4);
    int*   bhist   = (int*)alloc((size_t)NBUK * NBLK * 4);
    int*   bsum2   = (int*)alloc(NSCB * 4);
    unsigned* ebuk = (unsigned*)alloc((size_t)NE * 4);
    unsigned* csr  = (unsigned*)alloc((size_t)NE * 4);
    unsigned short* W1T = (unsigned short*)alloc((size_t)HID * INC * 2);

    hipLaunchKernelGGL(k_pre,    dim3(NBLK), dim3(256), 0, stream, col, bhist, W1, W1T, bnsum, bnsumsq);
    hipLaunchKernelGGL(k_gscanA, dim3(NSCB), dim3(GS_B), 0, stream, bhist, bhist, bsum2, NBUK * NBLK);
    hipLaunchKernelGGL(k_fuse1,  dim3(NBLK + G1A), dim3(256), 0, stream, row, col, bhist, bsum2, ebuk, x, W1T, h1b);
    hipLaunchKernelGGL(k_fuse2,  dim3(NBUK + G1B), dim3(256), 0, stream, ebuk, bhist, bsum2, deg, rowptr, x, W1T, h1b);
    hipLaunchKernelGGL(k_fuse3,  dim3(NBUK + G1C), dim3(256), 0, stream, ebuk, bhist, bsum2, rowptr, deg, csr, x, W1T, h1b);
    hipLaunchKernelGGL(k_agg1,   dim3(NN / 4), dim3(256), 0, stream, h1b, rowptr, csr, b1, aggb);
    hipLaunchKernelGGL(k_bnstats, dim3(256), dim3(256), 0, stream, aggb, bnsum, bnsumsq);
    hipLaunchKernelGGL(k_gemm2,  dim3((NN + 63) / 64), dim3(256), 0, stream, aggb, W2, bnsum, bnsumsq, gamma, beta, h2b);
    hipLaunchKernelGGL(k_agg2,   dim3(NN / 4), dim3(256), 0, stream, h2b, rowptr, csr, b2, out);
}